// Round 2
// baseline (1098.133 us; speedup 1.0000x reference)
//
#include <hip/hip_runtime.h>
#include <hip/hip_cooperative_groups.h>

namespace cg = cooperative_groups;

// PageRank R10 (resubmit — R10 bench hit GPUAcquisitionTimeout, never ran).
// R9 post-mortem: k5_iter = 250us for ONE effective iteration
// (err@iter0 ~ 0.17 < 1.0) with VALUBusy 1.7%, HBM 7% -> latency-bound serial
// chain (stream load -> gather w[col] -> LDS atomic) at 2 waves/SIMD.
// R10: (a) k5 scatter gets a 3-stage software pipeline (gathers 1 batch ahead,
// vec loads 2 ahead, static even/odd renaming); plain loads on the 96MB stream
// (L3-resident from k3b). (b) deg/bincount moves to fire-and-forget global
// atomics fused into k1's col stream; k3a/k4a/k4b + colp/hpart deleted;
// tiny k2c maps deg -> rdeg,w0 in place. All R7-R9 proven machinery for the
// row structure (rings, whole-wave flushes, LDS fixed-point) is kept.

static constexpr int   NN       = 1000000;
static constexpr int   NE       = 16000000;
static constexpr float ALPHA    = 0.85f;
static constexpr int   MAX_ITER = 100;
static constexpr float THRESH   = 1.0f;                      // float32(N)*1e-6
static constexpr float INV_N    = 1.0f / 1000000.0f;
static constexpr float TELEPORT = 0.15f * (1.0f / 1000000.0f);
static constexpr float SCALE    = 8796093022208.0f;          // 2^43
static constexpr float INVSCALE = 1.0f / 8796093022208.0f;

static constexpr int T     = 256;
static constexpr int NCH   = 2048;           // partition chunks (=K1/K3 grids)
static constexpr int BSH   = 14;
static constexpr int BKN   = 16384;          // nodes per bucket
static constexpr int NBK   = 64;             // buckets (62 used)
static constexpr int NSUBB = 496;            // 62 x 8 SpMV partials
static constexpr int NSLC  = 489;            // 2048-node merge slices
static constexpr int NDEG4 = 250000;         // NN/4 int4 groups of deg
static constexpr int GDEG  = 977;            // ceil(NDEG4/T)

// ws layout (bytes); colp/hpart regions of R9 are now dead (kept for layout)
static constexpr size_t OFF_WCG  = 0;                  // (NE+512) u32
static constexpr size_t OFF_WRG  = 64002048;           // (NE+512) u16
static constexpr size_t OFF_PACC = 96003072;           // 496*16384 i32
static constexpr size_t OFF_CNTR = 128508928;          // 64*2048 u32
static constexpr size_t OFF_CNTC = 129033216;          // (dead)
static constexpr size_t OFF_CTRL = 129557504;          // 4KB
static constexpr size_t OFF_RDEG = 129561600;          // 4,000,000 (deg->rdeg)
static constexpr size_t OFF_W    = 133561600;          // 4,000,032 (w[NN]=0)
static constexpr size_t NEED     = 137561632;

typedef int      vi4 __attribute__((ext_vector_type(4)));
typedef unsigned vu4 __attribute__((ext_vector_type(4)));

template<typename TT>
__device__ __forceinline__ TT ntload(const TT* p) { return __builtin_nontemporal_load(p); }

struct P {
    unsigned* wcg; unsigned short* wrg;
    int* pacc; unsigned* cntR; unsigned* cntC;
    float* rdeg; float* w;
    unsigned* totR; unsigned* totC; unsigned* baseR; unsigned* baseC;
    unsigned* flags; int* ovf; float* errF;
};
__device__ __forceinline__ P mk(char* ws) {
    P p;
    p.wcg  = (unsigned*)(ws + OFF_WCG);
    p.wrg  = (unsigned short*)(ws + OFF_WRG);
    p.pacc = (int*)(ws + OFF_PACC);
    p.cntR = (unsigned*)(ws + OFF_CNTR);
    p.cntC = (unsigned*)(ws + OFF_CNTC);
    unsigned* ctrl = (unsigned*)(ws + OFF_CTRL);
    p.rdeg = (float*)(ws + OFF_RDEG);
    p.w    = (float*)(ws + OFF_W);
    p.totR = ctrl; p.totC = ctrl + 64; p.baseR = ctrl + 128; p.baseC = ctrl + 200;
    p.flags = ctrl + 280; p.ovf = (int*)(ctrl + 281); p.errF = (float*)(ctrl + 288);
    return p;
}

// ---- atomic fallback (is64 input / ring overflow / small ws). No __shared__. ----
__device__ void atomic_fallback(cg::grid_group& grid, int is64,
                                const int* e32, const long long* e64,
                                int* ai, int* deg, float* rdeg,
                                float* vA, float* vB, float* w,
                                float* err, float* out,
                                int tid, int stride, int th)
{
    for (int i = tid; i < NN; i += stride) { ai[i] = 0; deg[i] = 0; vA[i] = INV_N; }
    grid.sync();
    if (is64) { const long long* cols = e64 + NE;
        for (int e = tid; e < NE; e += stride) atomicAdd(&deg[(int)cols[e]], 1); }
    else      { const int* cols = e32 + NE;
        for (int e = tid; e < NE; e += stride) atomicAdd(&deg[cols[e]], 1); }
    grid.sync();
    for (int i = tid; i < NN; i += stride) rdeg[i] = ALPHA / (float)deg[i];
    grid.sync();
    float* v = vA; float* nv = vB;
    for (int iter = 0; iter < MAX_ITER; ++iter) {
        for (int i = tid; i < NN; i += stride) { w[i] = v[i] * rdeg[i]; ai[i] = 0; }
        grid.sync();
        if (is64) { const long long* rows = e64; const long long* cols = e64 + NE;
            for (int e = tid; e < NE; e += stride)
                atomicAdd(&ai[(int)rows[e]], __float2int_rn(w[(int)cols[e]] * SCALE)); }
        else { const int* rows = e32; const int* cols = e32 + NE;
            for (int e = tid; e < NE; e += stride)
                atomicAdd(&ai[rows[e]], __float2int_rn(w[cols[e]] * SCALE)); }
        grid.sync();
        float pe = 0.0f;
        for (int i = tid; i < NN; i += stride) {
            float x = TELEPORT + (float)ai[i] * INVSCALE;
            pe += fabsf(x - v[i]); nv[i] = x;
        }
        #pragma unroll
        for (int off = 32; off > 0; off >>= 1) pe += __shfl_down(pe, off, 64);
        if ((th & 63) == 0) unsafeAtomicAdd(&err[iter], pe);
        grid.sync();
        float e = ((volatile float*)err)[iter];
        float* t = v; v = nv; nv = t;
        if (e < THRESH) break;
    }
    for (int i = tid; i < NN; i += stride) out[i] = v[i];
}

// ---------------- K0: deg zero + flags / control init ----------------
__global__ __launch_bounds__(256) void k0_init(const int* __restrict__ e32, char* ws)
{
    P p = mk(ws);
    __shared__ int snz;
    const int th = threadIdx.x;
    const int idx = blockIdx.x * T + th;
    if (idx < NDEG4) {                                 // zero deg (int4)
        vi4 z = {0, 0, 0, 0};
        *((vi4*)(ws + OFF_RDEG) + idx) = z;
    }
    if (blockIdx.x == 0) {
        if (th == 0) snz = 0;
        __syncthreads();
        if (e32[2 * th + 1] != 0) atomicOr(&snz, 1);   // int64 => high words all 0
        __syncthreads();
        if (th == 0) { p.flags[0] = (snz == 0) ? 1u : 0u; *p.ovf = 0; p.w[NN] = 0.0f; }
        if (th < MAX_ITER) p.errF[th] = 0.0f;
    }
}

// ---------------- K1: row-bucket histograms + global-atomic deg ----------------
__global__ __launch_bounds__(256, 8) void k1_hist(const int* __restrict__ e32, char* ws)
{
    P p = mk(ws);
    if (p.flags[0]) return;
    __shared__ int h[64];
    int* __restrict__ deg = (int*)(ws + OFF_RDEG);
    const int th = threadIdx.x, blk = blockIdx.x;
    const int e0 = (int)(((long long)NE * blk) >> 11);
    const int e1 = (int)(((long long)NE * (blk + 1)) >> 11);
    if (th < 64) h[th] = 0;
    __syncthreads();
    const vi4* R4 = (const vi4*)e32;
    const vi4* C4 = (const vi4*)(e32 + NE);
    const int qe = (e1 + 3) >> 2;
    for (int q = (e0 >> 2) + th; q < qe; q += T) {
        vi4 R = R4[q], C = C4[q];                  // plain loads: seed L3 for K3
        int rr[4] = {R.x, R.y, R.z, R.w}, cc[4] = {C.x, C.y, C.z, C.w};
        #pragma unroll
        for (int j = 0; j < 4; ++j) {
            int e = 4 * q + j;
            if (e >= e0 && e < e1) {
                atomicAdd(&h[rr[j] >> BSH], 1);
                atomicAdd(&deg[cc[j]], 1);         // fire-and-forget
            }
        }
    }
    __syncthreads();
    if (th < 64) p.cntR[(size_t)th * NCH + blk] = (unsigned)h[th];
}

// ---------------- K2: per-bucket exclusive scan over 2048 chunks (rows) ----------------
__global__ __launch_bounds__(256, 4) void k2_scan(char* ws)
{
    P p = mk(ws);
    if (p.flags[0]) return;
    __shared__ int S[256];
    const int th = threadIdx.x, b = blockIdx.x;       // 64 blocks
    unsigned* cnt = p.cntR + (size_t)b * NCH;
    unsigned v[8]; unsigned s = 0;
    #pragma unroll
    for (int i = 0; i < 8; ++i) { v[i] = cnt[8 * th + i]; s += v[i]; }
    S[th] = (int)s; __syncthreads();
    for (int off = 1; off < 256; off <<= 1) {
        int x = (th >= off) ? S[th - off] : 0;
        __syncthreads(); S[th] += x; __syncthreads();
    }
    unsigned run = (unsigned)S[th] - s;
    #pragma unroll
    for (int i = 0; i < 8; ++i) { unsigned t = v[i]; cnt[8 * th + i] = run; run += t; }
    if (th == 255) p.totR[b] = run;
}

// ---------------- K2b: padded row bases ----------------
__global__ __launch_bounds__(256) void k2b_bases(char* ws)
{
    P p = mk(ws);
    if (p.flags[0]) return;
    __shared__ int S[64];
    const int th = threadIdx.x;
    unsigned pt = 0;
    if (th < 64) {
        unsigned t = p.totR[th];
        pt = (t + 7u) & ~7u;
        S[th] = (int)pt;
    }
    __syncthreads();
    for (int off = 1; off < 64; off <<= 1) {
        int x = (th < 64 && th >= off) ? S[th - off] : 0;
        __syncthreads(); if (th < 64) S[th] += x; __syncthreads();
    }
    if (th < 64) {
        p.baseR[th] = (unsigned)S[th] - pt;
        if (th == 63) p.baseR[64] = (unsigned)S[63];
    }
}

// ---------------- K2c: deg -> rdeg (in place) + w0 ----------------
__global__ __launch_bounds__(256) void k2c_rdeg(char* ws)
{
    P p = mk(ws);
    if (p.flags[0]) return;
    const int idx = blockIdx.x * T + threadIdx.x;
    if (idx >= NDEG4) return;
    const vi4 d = *((const vi4*)(const void*)p.rdeg + idx);
    float4 r;
    r.x = ALPHA / (float)d.x;    // deg==0 -> inf, never gathered
    r.y = ALPHA / (float)d.y;
    r.z = ALPHA / (float)d.z;
    r.w = ALPHA / (float)d.w;
    *((float4*)p.rdeg + idx) = r;
    float4 w0 = {INV_N * r.x, INV_N * r.y, INV_N * r.z, INV_N * r.w};
    *((float4*)p.w + idx) = w0;                       // fused iter-0 phase A
}

// ---------------- K3b: row scatter (u32 c + u16 r_low), register-pipelined ----------------
__global__ __launch_bounds__(256, 3) void k3b_row(const int* __restrict__ e32, char* ws)
{
    P p = mk(ws);
    if (p.flags[0] || *p.ovf) return;
    __shared__ int SH3[12480];
    int*            wcL = SH3;                               // [64][128] u32
    unsigned short* wrL = (unsigned short*)(SH3 + 8192);     // [64][128] u16
    int* fills = SH3 + 12288; int* flsh = SH3 + 12352; int* wpos = SH3 + 12416;
    const int th = threadIdx.x, blk = blockIdx.x;
    if (blk < 64 && th == 0) {                               // row pads
        unsigned tot = p.totR[blk], bs = p.baseR[blk], pt = (tot + 7u) & ~7u;
        for (unsigned i = tot; i < pt; ++i) { p.wcg[bs + i] = (unsigned)NN; p.wrg[bs + i] = 0; }
    }
    if (th < 64) { fills[th] = 0; flsh[th] = 0;
                   wpos[th] = (int)(p.baseR[th] + p.cntR[(size_t)th * NCH + blk]); }
    __syncthreads();
    const int e0 = (int)(((long long)NE * blk) >> 11);
    const int e1 = (int)(((long long)NE * (blk + 1)) >> 11);
    const vi4* R4 = (const vi4*)e32;
    const vi4* C4 = (const vi4*)(e32 + NE);
    const int qs = e0 >> 2, qe = (e1 + 3) >> 2;
    vi4 Rcur = {0,0,0,0}, Ccur = {0,0,0,0};
    if (qs + th < qe) { Rcur = R4[qs + th]; Ccur = C4[qs + th]; }
    for (int qb = qs; qb < qe; qb += T) {
        vi4 Rnext = {0,0,0,0}, Cnext = {0,0,0,0};
        { int qn = qb + T + th; if (qn < qe) { Rnext = R4[qn]; Cnext = C4[qn]; } }
        const int q = qb + th;
        if (q < qe) {
            int rr[4] = {Rcur.x, Rcur.y, Rcur.z, Rcur.w};
            int cc[4] = {Ccur.x, Ccur.y, Ccur.z, Ccur.w};
            #pragma unroll
            for (int j = 0; j < 4; ++j) {
                int e = 4 * q + j;
                if (e >= e0 && e < e1) {
                    int bb = rr[j] >> BSH;
                    int idx = atomicAdd(&fills[bb], 1);
                    int sl = idx & 127;
                    wcL[bb * 128 + sl] = cc[j];
                    wrL[bb * 128 + sl] = (unsigned short)(rr[j] & (BKN - 1));
                }
            }
        }
        __syncthreads();
        const int wv = th >> 6, lane = th & 63;
        for (int k = 0; k < 16; ++k) {
            const int b = wv * 16 + k;
            int ff = fills[b], fl = flsh[b], wp = wpos[b];
            if (ff - fl > 128) *p.ovf = 1;
            while (ff - fl >= 64) {
                p.wcg[wp + lane] = (unsigned)wcL[b * 128 + ((fl + lane) & 127)];
                p.wrg[wp + lane] = wrL[b * 128 + ((fl + lane) & 127)];
                fl += 64; wp += 64;
            }
            if (lane == 0) { flsh[b] = fl; wpos[b] = wp; }
        }
        __syncthreads();
        Rcur = Rnext; Ccur = Cnext;
    }
    {   // drain
        const int wv = th >> 6, lane = th & 63;
        for (int k = 0; k < 16; ++k) {
            const int b = wv * 16 + k;
            int ff = fills[b], fl = flsh[b], wp = wpos[b];
            while (ff > fl) {
                int n = min(64, ff - fl);
                if (lane < n) {
                    p.wcg[wp + lane] = (unsigned)wcL[b * 128 + ((fl + lane) & 127)];
                    p.wrg[wp + lane] = wrL[b * 128 + ((fl + lane) & 127)];
                }
                fl += n; wp += n;
            }
        }
    }
}

// gather 8 w values for one batch; save the rl word alongside
#define GATH(G, CA, CB)                              \
    G##0 = w[(unsigned)CA.x]; G##1 = w[(unsigned)CA.y]; \
    G##2 = w[(unsigned)CA.z]; G##3 = w[(unsigned)CA.w]; \
    G##4 = w[(unsigned)CB.x]; G##5 = w[(unsigned)CB.y]; \
    G##6 = w[(unsigned)CB.z]; G##7 = w[(unsigned)CB.w];

#define ATOM(RL, G)                                                         \
    atomicAdd(&SH[RL.x & 0xFFFFu], __float2int_rn(G##0 * SCALE));           \
    atomicAdd(&SH[RL.x >> 16],     __float2int_rn(G##1 * SCALE));           \
    atomicAdd(&SH[RL.y & 0xFFFFu], __float2int_rn(G##2 * SCALE));           \
    atomicAdd(&SH[RL.y >> 16],     __float2int_rn(G##3 * SCALE));           \
    atomicAdd(&SH[RL.z & 0xFFFFu], __float2int_rn(G##4 * SCALE));           \
    atomicAdd(&SH[RL.z >> 16],     __float2int_rn(G##5 * SCALE));           \
    atomicAdd(&SH[RL.w & 0xFFFFu], __float2int_rn(G##6 * SCALE));           \
    atomicAdd(&SH[RL.w >> 16],     __float2int_rn(G##7 * SCALE));

// ---------------- K5: cooperative iteration loop (early exit) ----------------
__global__ __launch_bounds__(256, 2)
void k5_iter(const int* __restrict__ e32, const long long* __restrict__ e64,
             char* __restrict__ ws, float* __restrict__ out)
{
    cg::grid_group grid = cg::this_grid();
    P p = mk(ws);
    const int th = threadIdx.x, blk = blockIdx.x;
    const int tid = blk * T + th;
    const int stride = gridDim.x * T;
    __shared__ int SH[16384];
    __shared__ float sred[4];

    if (p.flags[0] || *p.ovf) {
        atomic_fallback(grid, (int)p.flags[0], e32, e64,
                        (int*)ws, (int*)(ws + (size_t)4*1024*1024), p.rdeg,
                        (float*)(ws + (size_t)8*1024*1024),
                        (float*)(ws + (size_t)12*1024*1024),
                        (float*)(ws + (size_t)16*1024*1024),
                        p.errF, out, tid, stride, th);
        return;
    }

    for (int iter = 0; iter < MAX_ITER; ++iter) {
        if (blk < NSUBB) {
            const int b = blk >> 3, sub = blk & 7;
            for (int j = th; j < 16384; j += T) SH[j] = 0;
            __syncthreads();
            const unsigned bs = p.baseR[b], tot = p.totR[b], pt = (tot + 7u) & ~7u;
            const unsigned nq = pt >> 3;
            const unsigned qlo = (nq * (unsigned)sub) >> 3;
            const unsigned qhi = (nq * (unsigned)(sub + 1)) >> 3;
            const vu4* __restrict__ r8 = (const vu4*)p.wrg + (bs >> 3);
            const vi4* __restrict__ c8 = (const vi4*)p.wcg + (bs >> 2);
            const float* __restrict__ w = p.w;

            // 3-stage pipeline: vec loads 2 batches ahead, gathers 1 ahead,
            // static even/odd renaming (no runtime-indexed arrays).
            unsigned q = qlo + th;
            vu4 rlA = {0,0,0,0}, rlB = {0,0,0,0}, rgA = {0,0,0,0}, rgB = {0,0,0,0};
            vi4 caA = {0,0,0,0}, cbA = {0,0,0,0}, caB = {0,0,0,0}, cbB = {0,0,0,0};
            float gA0=0,gA1=0,gA2=0,gA3=0,gA4=0,gA5=0,gA6=0,gA7=0;
            float gB0=0,gB1=0,gB2=0,gB3=0,gB4=0,gB5=0,gB6=0,gB7=0;
            if (q < qhi)     { rlA = r8[q];     caA = c8[2*q];       cbA = c8[2*q+1]; }
            if (q + T < qhi) { rlB = r8[q+T];   caB = c8[2*(q+T)];   cbB = c8[2*(q+T)+1]; }
            if (q < qhi)     { GATH(gA, caA, cbA); rgA = rlA; }
            while (q < qhi) {
                // even: gather B (issued before A's atomics), prefetch vec q+2T into A slots
                if (q + T < qhi)   { GATH(gB, caB, cbB); rgB = rlB; }
                if (q + 2*T < qhi) { rlA = r8[q+2*T]; caA = c8[2*(q+2*T)]; cbA = c8[2*(q+2*T)+1]; }
                ATOM(rgA, gA);
                q += T;
                if (q >= qhi) break;
                // odd: gather A, prefetch vec q+2T into B slots
                if (q + T < qhi)   { GATH(gA, caA, cbA); rgA = rlA; }
                if (q + 2*T < qhi) { rlB = r8[q+2*T]; caB = c8[2*(q+2*T)]; cbB = c8[2*(q+2*T)+1]; }
                ATOM(rgB, gB);
                q += T;
            }
            __syncthreads();
            vi4* pa = (vi4*)(p.pacc + (size_t)blk * 16384);
            const vi4* s4 = (const vi4*)SH;
            for (int j = th; j < 4096; j += T)
                __builtin_nontemporal_store(s4[j], pa + j);
        }
        grid.sync();

        float pe = 0.0f;
        if (blk < NSLC) {
            const int b = blk >> 3, off = (blk & 7) * 2048;
            for (int g = th; g < 512; g += T) {
                int node = b * BKN + off + 4 * g;
                if (node < NN) {
                    vi4 acc = {0, 0, 0, 0};
                    #pragma unroll
                    for (int qq = 0; qq < 8; ++qq) {
                        const vi4* pp = (const vi4*)(p.pacc + (size_t)(b*8+qq)*16384 + off);
                        vi4 x = ntload(pp + g);
                        acc.x += x.x; acc.y += x.y; acc.z += x.z; acc.w += x.w;
                    }
                    float x0 = TELEPORT + (float)acc.x * INVSCALE;
                    float x1 = TELEPORT + (float)acc.y * INVSCALE;
                    float x2 = TELEPORT + (float)acc.z * INVSCALE;
                    float x3 = TELEPORT + (float)acc.w * INVSCALE;
                    float4 prev;
                    if (iter == 0) prev = make_float4(INV_N, INV_N, INV_N, INV_N);
                    else           prev = *(const float4*)&out[node];
                    pe += fabsf(x0 - prev.x) + fabsf(x1 - prev.y)
                        + fabsf(x2 - prev.z) + fabsf(x3 - prev.w);
                    float4 nv = {x0, x1, x2, x3};
                    *(float4*)&out[node] = nv;                 // v lives in out
                    float4 rd = *(const float4*)&p.rdeg[node];
                    float4 nw = {x0*rd.x, x1*rd.y, x2*rd.z, x3*rd.w};
                    *(float4*)&p.w[node] = nw;                 // fused next phase A
                }
            }
            #pragma unroll
            for (int o2 = 32; o2 > 0; o2 >>= 1) pe += __shfl_down(pe, o2, 64);
            if ((th & 63) == 0) sred[th >> 6] = pe;
            __syncthreads();
            if (th == 0)
                unsafeAtomicAdd(&p.errF[iter], sred[0] + sred[1] + sred[2] + sred[3]);
        }
        grid.sync();
        const float e = ((volatile float*)p.errF)[iter];
        if (e < THRESH) break;
    }
}

// ---- emergency fallback kernel (ws too small / occupancy short) ----
__global__ __launch_bounds__(256, 4)
void pagerank_atomic(const int* __restrict__ e32, const long long* __restrict__ e64,
                     int* __restrict__ ai, int* __restrict__ deg,
                     float* __restrict__ rdeg, float* __restrict__ vA,
                     float* __restrict__ vB, float* __restrict__ w,
                     float* __restrict__ err, int* __restrict__ flags,
                     float* __restrict__ out)
{
    cg::grid_group grid = cg::this_grid();
    const int tid = blockIdx.x * blockDim.x + threadIdx.x;
    const int stride = gridDim.x * blockDim.x;
    if (tid < MAX_ITER) err[tid] = 0.0f;
    if (tid == 0) {
        int nz = 0;
        for (int k = 1; k < 512; k += 2) nz |= e32[k];
        flags[0] = (nz == 0) ? 1 : 0;
    }
    grid.sync();
    atomic_fallback(grid, flags[0], e32, e64, ai, deg, rdeg, vA, vB, w, err, out,
                    tid, stride, threadIdx.x);
}

extern "C" void kernel_launch(void* const* d_in, const int* in_sizes, int n_in,
                              void* d_out, int out_size, void* d_ws, size_t ws_size,
                              hipStream_t stream)
{
    (void)n_in; (void)out_size; (void)in_sizes;
    const int*       e32 = (const int*)d_in[1];
    const long long* e64 = (const long long*)d_in[1];
    float* out = (float*)d_out;
    char*  ws  = (char*)d_ws;

    int occ = 0;
    hipOccupancyMaxActiveBlocksPerMultiprocessor(&occ, (const void*)k5_iter, T, 0);

    if (ws_size >= NEED && occ >= 2) {
        k0_init<<<GDEG, T, 0, stream>>>(e32, ws);
        k1_hist<<<NCH,  T, 0, stream>>>(e32, ws);
        k2_scan<<<64,   T, 0, stream>>>(ws);
        k2b_bases<<<1,  T, 0, stream>>>(ws);
        k2c_rdeg<<<GDEG,T, 0, stream>>>(ws);
        k3b_row<<<NCH,  T, 0, stream>>>(e32, ws);
        void* args[] = { (void*)&e32, (void*)&e64, (void*)&ws, (void*)&out };
        hipLaunchCooperativeKernel((const void*)k5_iter,
                                   dim3(512), dim3(T), args, 0, stream);
        return;
    }

    // emergency: device-atomic version, small footprint
    const size_t MB = 1024 * 1024;
    int*   ai    = (int*)(ws);
    int*   deg   = (int*)(ws + 4 * MB);
    float* rdeg  = (float*)(ws + 8 * MB);
    float* vA    = (float*)(ws + 12 * MB);
    float* vB    = (float*)(ws + 16 * MB);
    float* w     = (float*)(ws + 20 * MB);
    float* err   = (float*)(ws + 24 * MB);
    int*   flg   = (int*)(ws + 24 * MB + 4096);
    int occ2 = 0;
    hipOccupancyMaxActiveBlocksPerMultiprocessor(&occ2, (const void*)pagerank_atomic, 256, 0);
    if (occ2 < 1) occ2 = 1;
    int grid = occ2 * 256; if (grid > 2048) grid = 2048;
    void* args[] = { (void*)&e32, (void*)&e64, (void*)&ai, (void*)&deg, (void*)&rdeg,
                     (void*)&vA, (void*)&vB, (void*)&w, (void*)&err, (void*)&flg,
                     (void*)&out };
    hipLaunchCooperativeKernel((const void*)pagerank_atomic,
                               dim3(grid), dim3(256), args, 0, stream);
}

// Round 3
// 645.591 us; speedup vs baseline: 1.7010x; 1.7010x over previous
//
#include <hip/hip_runtime.h>
#include <hip/hip_cooperative_groups.h>

namespace cg = cooperative_groups;

// PageRank R11. R10 post-mortem: fused global-atomic deg histogram cost 609us
// in k1 (WRITE_SIZE 504MB = 16M atomics x 32B write-through per atomic + TCC
// line serialization, 26 G atomics/s) -> total regressed 618->1098. HW fact
// learned: random device-scope atomics = ~32B HBM write EACH; never bulk-hist.
// R11: revert deg to R9's col bucket-scatter (k3a, LDS-atomic rings), but
// replace k4a(496 partials)+k4b(merge) with ONE fused k4_deg: 62 blocks, one
// per bucket, full 16K-counter LDS histogram -> rdeg/w0 directly (no 32MB
// hpart traffic, 2 fewer launches). k5 keeps R10's 3-stage pipeline (proven
// correct in R10: absmax 7.5e-09) so this round finally measures it.

static constexpr int   NN       = 1000000;
static constexpr int   NE       = 16000000;
static constexpr float ALPHA    = 0.85f;
static constexpr int   MAX_ITER = 100;
static constexpr float THRESH   = 1.0f;                      // float32(N)*1e-6
static constexpr float INV_N    = 1.0f / 1000000.0f;
static constexpr float TELEPORT = 0.15f * (1.0f / 1000000.0f);
static constexpr float SCALE    = 8796093022208.0f;          // 2^43
static constexpr float INVSCALE = 1.0f / 8796093022208.0f;

static constexpr int T     = 256;
static constexpr int NCH   = 2048;           // partition chunks (=K1/K3 grids)
static constexpr int BSH   = 14;
static constexpr int BKN   = 16384;          // nodes per bucket
static constexpr int NBK   = 64;             // buckets (62 used)
static constexpr int NBKU  = 62;             // used buckets
static constexpr int NSUBB = 496;            // 62 x 8 SpMV partials
static constexpr int NSLC  = 489;            // 2048-node merge slices

// ws layout (bytes); colp overlays wcg (dead before K3b writes wcg)
static constexpr size_t OFF_WCG  = 0;                  // (NE+512) u32
static constexpr size_t OFF_COLP = 0;                  // (NE+512) u16 overlay
static constexpr size_t OFF_WRG  = 64002048;           // (NE+512) u16
static constexpr size_t OFF_PACC = 96003072;           // 496*16384 i32
static constexpr size_t OFF_CNTR = 128508928;          // 64*2048 u32
static constexpr size_t OFF_CNTC = 129033216;          // 64*2048 u32
static constexpr size_t OFF_CTRL = 129557504;          // 4KB
static constexpr size_t OFF_RDEG = 129561600;          // 4,000,000
static constexpr size_t OFF_W    = 133561600;          // 4,000,032 (w[NN]=0)
static constexpr size_t NEED     = 137561632;

typedef int      vi4 __attribute__((ext_vector_type(4)));
typedef unsigned vu4 __attribute__((ext_vector_type(4)));

template<typename TT>
__device__ __forceinline__ TT ntload(const TT* p) { return __builtin_nontemporal_load(p); }

struct P {
    unsigned* wcg; unsigned short* colp; unsigned short* wrg;
    int* pacc; unsigned* cntR; unsigned* cntC;
    float* rdeg; float* w;
    unsigned* totR; unsigned* totC; unsigned* baseR; unsigned* baseC;
    unsigned* flags; int* ovf; float* errF;
};
__device__ __forceinline__ P mk(char* ws) {
    P p;
    p.wcg  = (unsigned*)(ws + OFF_WCG);
    p.colp = (unsigned short*)(ws + OFF_COLP);
    p.wrg  = (unsigned short*)(ws + OFF_WRG);
    p.pacc = (int*)(ws + OFF_PACC);
    p.cntR = (unsigned*)(ws + OFF_CNTR);
    p.cntC = (unsigned*)(ws + OFF_CNTC);
    unsigned* ctrl = (unsigned*)(ws + OFF_CTRL);
    p.rdeg = (float*)(ws + OFF_RDEG);
    p.w    = (float*)(ws + OFF_W);
    p.totR = ctrl; p.totC = ctrl + 64; p.baseR = ctrl + 128; p.baseC = ctrl + 200;
    p.flags = ctrl + 280; p.ovf = (int*)(ctrl + 281); p.errF = (float*)(ctrl + 288);
    return p;
}

// ---- atomic fallback (is64 input / ring overflow / small ws). No __shared__. ----
__device__ void atomic_fallback(cg::grid_group& grid, int is64,
                                const int* e32, const long long* e64,
                                int* ai, int* deg, float* rdeg,
                                float* vA, float* vB, float* w,
                                float* err, float* out,
                                int tid, int stride, int th)
{
    for (int i = tid; i < NN; i += stride) { ai[i] = 0; deg[i] = 0; vA[i] = INV_N; }
    grid.sync();
    if (is64) { const long long* cols = e64 + NE;
        for (int e = tid; e < NE; e += stride) atomicAdd(&deg[(int)cols[e]], 1); }
    else      { const int* cols = e32 + NE;
        for (int e = tid; e < NE; e += stride) atomicAdd(&deg[cols[e]], 1); }
    grid.sync();
    for (int i = tid; i < NN; i += stride) rdeg[i] = ALPHA / (float)deg[i];
    grid.sync();
    float* v = vA; float* nv = vB;
    for (int iter = 0; iter < MAX_ITER; ++iter) {
        for (int i = tid; i < NN; i += stride) { w[i] = v[i] * rdeg[i]; ai[i] = 0; }
        grid.sync();
        if (is64) { const long long* rows = e64; const long long* cols = e64 + NE;
            for (int e = tid; e < NE; e += stride)
                atomicAdd(&ai[(int)rows[e]], __float2int_rn(w[(int)cols[e]] * SCALE)); }
        else { const int* rows = e32; const int* cols = e32 + NE;
            for (int e = tid; e < NE; e += stride)
                atomicAdd(&ai[rows[e]], __float2int_rn(w[cols[e]] * SCALE)); }
        grid.sync();
        float pe = 0.0f;
        for (int i = tid; i < NN; i += stride) {
            float x = TELEPORT + (float)ai[i] * INVSCALE;
            pe += fabsf(x - v[i]); nv[i] = x;
        }
        #pragma unroll
        for (int off = 32; off > 0; off >>= 1) pe += __shfl_down(pe, off, 64);
        if ((th & 63) == 0) unsafeAtomicAdd(&err[iter], pe);
        grid.sync();
        float e = ((volatile float*)err)[iter];
        float* t = v; v = nv; nv = t;
        if (e < THRESH) break;
    }
    for (int i = tid; i < NN; i += stride) out[i] = v[i];
}

// ---------------- K0: flags / control init ----------------
__global__ __launch_bounds__(256) void k0_init(const int* __restrict__ e32, char* ws)
{
    P p = mk(ws);
    __shared__ int snz;
    const int th = threadIdx.x;
    if (th == 0) snz = 0;
    __syncthreads();
    if (e32[2 * th + 1] != 0) atomicOr(&snz, 1);   // int64 => high words all 0
    __syncthreads();
    if (th == 0) { p.flags[0] = (snz == 0) ? 1u : 0u; *p.ovf = 0; p.w[NN] = 0.0f; }
    if (th < MAX_ITER) p.errF[th] = 0.0f;
}

// ---------------- K1: per-chunk bucket histograms (rows + cols, LDS only) ----------------
__global__ __launch_bounds__(256, 8) void k1_hist(const int* __restrict__ e32, char* ws)
{
    P p = mk(ws);
    if (p.flags[0]) return;
    __shared__ int h[128];
    const int th = threadIdx.x, blk = blockIdx.x;
    const int e0 = (int)(((long long)NE * blk) >> 11);
    const int e1 = (int)(((long long)NE * (blk + 1)) >> 11);
    if (th < 128) h[th] = 0;
    __syncthreads();
    const vi4* R4 = (const vi4*)e32;
    const vi4* C4 = (const vi4*)(e32 + NE);
    const int qe = (e1 + 3) >> 2;
    for (int q = (e0 >> 2) + th; q < qe; q += T) {
        vi4 R = R4[q], C = C4[q];                  // plain loads: seed L3 for K3
        int rr[4] = {R.x, R.y, R.z, R.w}, cc[4] = {C.x, C.y, C.z, C.w};
        #pragma unroll
        for (int j = 0; j < 4; ++j) {
            int e = 4 * q + j;
            if (e >= e0 && e < e1) {
                atomicAdd(&h[rr[j] >> BSH], 1);
                atomicAdd(&h[64 + (cc[j] >> BSH)], 1);
            }
        }
    }
    __syncthreads();
    if (th < 64) {
        p.cntR[(size_t)th * NCH + blk] = (unsigned)h[th];
        p.cntC[(size_t)th * NCH + blk] = (unsigned)h[64 + th];
    }
}

// ---------------- K2: per-bucket exclusive scan over 2048 chunks ----------------
__global__ __launch_bounds__(256, 4) void k2_scan(char* ws)
{
    P p = mk(ws);
    if (p.flags[0]) return;
    __shared__ int S[256];
    const int th = threadIdx.x, blk = blockIdx.x;     // 128 blocks
    const int side = blk >> 6, b = blk & 63;
    unsigned* cnt = (side ? p.cntC : p.cntR) + (size_t)b * NCH;
    unsigned v[8]; unsigned s = 0;
    #pragma unroll
    for (int i = 0; i < 8; ++i) { v[i] = cnt[8 * th + i]; s += v[i]; }
    S[th] = (int)s; __syncthreads();
    for (int off = 1; off < 256; off <<= 1) {
        int x = (th >= off) ? S[th - off] : 0;
        __syncthreads(); S[th] += x; __syncthreads();
    }
    unsigned run = (unsigned)S[th] - s;
    #pragma unroll
    for (int i = 0; i < 8; ++i) { unsigned t = v[i]; cnt[8 * th + i] = run; run += t; }
    if (th == 255) (side ? p.totC : p.totR)[b] = run;
}

// ---------------- K2b: padded bases + col pads ----------------
__global__ __launch_bounds__(256) void k2b_bases(char* ws)
{
    P p = mk(ws);
    if (p.flags[0]) return;
    __shared__ int S[128];
    const int th = threadIdx.x;
    unsigned pt = 0;
    if (th < 128) {
        unsigned t = (th < 64) ? p.totR[th] : p.totC[th - 64];
        pt = (t + 7u) & ~7u;
        S[th] = (int)pt;
    }
    __syncthreads();
    for (int off = 1; off < 64; off <<= 1) {
        int x = (th < 128 && (th & 63) >= off) ? S[th - off] : 0;
        __syncthreads(); if (th < 128) S[th] += x; __syncthreads();
    }
    if (th < 64) {
        p.baseR[th] = (unsigned)S[th] - pt;
        if (th == 63) p.baseR[64] = (unsigned)S[63];
    } else if (th < 128) {
        p.baseC[th - 64] = (unsigned)S[th] - pt;
        if (th == 127) p.baseC[64] = (unsigned)S[127];
    }
    __syncthreads();
    if (th < 64) {                                   // col pads (deg corrected in K4)
        unsigned tot = p.totC[th], bs = p.baseC[th], pp = (tot + 7u) & ~7u;
        for (unsigned i = tot; i < pp; ++i) p.colp[bs + i] = 0;
    }
}

// ---------------- K3a: col scatter (u16), register-pipelined ----------------
__global__ __launch_bounds__(256, 6) void k3a_col(const int* __restrict__ e32, char* ws)
{
    P p = mk(ws);
    if (p.flags[0]) return;
    __shared__ int SH3[4288];
    unsigned short* pcL = (unsigned short*)SH3;              // [64][128]
    int* fills = SH3 + 4096; int* flsh = SH3 + 4160; int* wpos = SH3 + 4224;
    const int th = threadIdx.x, blk = blockIdx.x;
    if (th < 64) { fills[th] = 0; flsh[th] = 0;
                   wpos[th] = (int)(p.baseC[th] + p.cntC[(size_t)th * NCH + blk]); }
    __syncthreads();
    const int e0 = (int)(((long long)NE * blk) >> 11);
    const int e1 = (int)(((long long)NE * (blk + 1)) >> 11);
    const vi4* C4 = (const vi4*)(e32 + NE);
    const int qs = e0 >> 2, qe = (e1 + 3) >> 2;
    vi4 Ccur = {0, 0, 0, 0}; if (qs + th < qe) Ccur = C4[qs + th];
    for (int qb = qs; qb < qe; qb += T) {
        vi4 Cnext = {0, 0, 0, 0};
        { int qn = qb + T + th; if (qn < qe) Cnext = C4[qn]; }   // prefetch next batch
        const int q = qb + th;
        if (q < qe) {
            int cc[4] = {Ccur.x, Ccur.y, Ccur.z, Ccur.w};
            #pragma unroll
            for (int j = 0; j < 4; ++j) {
                int e = 4 * q + j;
                if (e >= e0 && e < e1) {
                    int bb = cc[j] >> BSH;
                    int idx = atomicAdd(&fills[bb], 1);
                    pcL[bb * 128 + (idx & 127)] = (unsigned short)(cc[j] & (BKN - 1));
                }
            }
        }
        __syncthreads();
        const int wv = th >> 6, lane = th & 63;
        for (int k = 0; k < 16; ++k) {
            const int b = wv * 16 + k;
            int ff = fills[b], fl = flsh[b], wp = wpos[b];
            if (ff - fl > 128) *p.ovf = 1;
            while (ff - fl >= 64) {
                p.colp[wp + lane] = pcL[b * 128 + ((fl + lane) & 127)];
                fl += 64; wp += 64;
            }
            if (lane == 0) { flsh[b] = fl; wpos[b] = wp; }
        }
        __syncthreads();
        Ccur = Cnext;
    }
    {   // drain
        const int wv = th >> 6, lane = th & 63;
        for (int k = 0; k < 16; ++k) {
            const int b = wv * 16 + k;
            int ff = fills[b], fl = flsh[b], wp = wpos[b];
            while (ff > fl) {
                int n = min(64, ff - fl);
                if (lane < n) p.colp[wp + lane] = pcL[b * 128 + ((fl + lane) & 127)];
                fl += n; wp += n;
            }
        }
    }
}

// ---------------- K4: fused per-bucket deg histogram -> rdeg, w0 ----------------
// One block per bucket (62): full 16K-counter LDS histogram over the bucket's
// colp slice, pad-corrected, then rdeg/w0 written directly. Replaces R9's
// k4a (496 partials, 16MB hpart) + k4b (merge) with zero intermediate traffic.
__global__ __launch_bounds__(256, 2) void k4_deg(char* ws)
{
    P p = mk(ws);
    if (p.flags[0] || *p.ovf) return;
    __shared__ int SH[16384];
    const int th = threadIdx.x, b = blockIdx.x;              // 62 blocks
    for (int j = th; j < 16384; j += T) SH[j] = 0;
    __syncthreads();
    const unsigned bs = p.baseC[b], tot = p.totC[b], pt = (tot + 7u) & ~7u;
    const unsigned nq = pt >> 3;
    const vu4* p8 = (const vu4*)p.colp + (bs >> 3);
    for (unsigned q = th; q < nq; q += T) {
        vu4 x = ntload(p8 + q);
        atomicAdd(&SH[x.x & 0xFFFFu], 1); atomicAdd(&SH[x.x >> 16], 1);
        atomicAdd(&SH[x.y & 0xFFFFu], 1); atomicAdd(&SH[x.y >> 16], 1);
        atomicAdd(&SH[x.z & 0xFFFFu], 1); atomicAdd(&SH[x.z >> 16], 1);
        atomicAdd(&SH[x.w & 0xFFFFu], 1); atomicAdd(&SH[x.w >> 16], 1);
    }
    __syncthreads();
    if (th == 0) SH[0] -= (int)(pt - tot);                   // pad correction
    __syncthreads();
    for (int g = th; g < 4096; g += T) {
        int node = b * BKN + 4 * g;
        if (node < NN) {                                     // node is 4-aligned; NN%4==0
            float r0 = ALPHA / (float)SH[4*g+0];             // deg==0 -> inf, never gathered
            float r1 = ALPHA / (float)SH[4*g+1];
            float r2 = ALPHA / (float)SH[4*g+2];
            float r3 = ALPHA / (float)SH[4*g+3];
            float4 rr = {r0, r1, r2, r3};
            *(float4*)&p.rdeg[node] = rr;
            float4 ww = {INV_N * r0, INV_N * r1, INV_N * r2, INV_N * r3};
            *(float4*)&p.w[node] = ww;                       // fused iter-0 phase A
        }
    }
}

// ---------------- K3b: row scatter (u32 c + u16 r_low), register-pipelined ----------------
__global__ __launch_bounds__(256, 3) void k3b_row(const int* __restrict__ e32, char* ws)
{
    P p = mk(ws);
    if (p.flags[0] || *p.ovf) return;
    __shared__ int SH3[12480];
    int*            wcL = SH3;                               // [64][128] u32
    unsigned short* wrL = (unsigned short*)(SH3 + 8192);     // [64][128] u16
    int* fills = SH3 + 12288; int* flsh = SH3 + 12352; int* wpos = SH3 + 12416;
    const int th = threadIdx.x, blk = blockIdx.x;
    if (blk < 64 && th == 0) {                               // row pads
        unsigned tot = p.totR[blk], bs = p.baseR[blk], pt = (tot + 7u) & ~7u;
        for (unsigned i = tot; i < pt; ++i) { p.wcg[bs + i] = (unsigned)NN; p.wrg[bs + i] = 0; }
    }
    if (th < 64) { fills[th] = 0; flsh[th] = 0;
                   wpos[th] = (int)(p.baseR[th] + p.cntR[(size_t)th * NCH + blk]); }
    __syncthreads();
    const int e0 = (int)(((long long)NE * blk) >> 11);
    const int e1 = (int)(((long long)NE * (blk + 1)) >> 11);
    const vi4* R4 = (const vi4*)e32;
    const vi4* C4 = (const vi4*)(e32 + NE);
    const int qs = e0 >> 2, qe = (e1 + 3) >> 2;
    vi4 Rcur = {0,0,0,0}, Ccur = {0,0,0,0};
    if (qs + th < qe) { Rcur = R4[qs + th]; Ccur = C4[qs + th]; }
    for (int qb = qs; qb < qe; qb += T) {
        vi4 Rnext = {0,0,0,0}, Cnext = {0,0,0,0};
        { int qn = qb + T + th; if (qn < qe) { Rnext = R4[qn]; Cnext = C4[qn]; } }
        const int q = qb + th;
        if (q < qe) {
            int rr[4] = {Rcur.x, Rcur.y, Rcur.z, Rcur.w};
            int cc[4] = {Ccur.x, Ccur.y, Ccur.z, Ccur.w};
            #pragma unroll
            for (int j = 0; j < 4; ++j) {
                int e = 4 * q + j;
                if (e >= e0 && e < e1) {
                    int bb = rr[j] >> BSH;
                    int idx = atomicAdd(&fills[bb], 1);
                    int sl = idx & 127;
                    wcL[bb * 128 + sl] = cc[j];
                    wrL[bb * 128 + sl] = (unsigned short)(rr[j] & (BKN - 1));
                }
            }
        }
        __syncthreads();
        const int wv = th >> 6, lane = th & 63;
        for (int k = 0; k < 16; ++k) {
            const int b = wv * 16 + k;
            int ff = fills[b], fl = flsh[b], wp = wpos[b];
            if (ff - fl > 128) *p.ovf = 1;
            while (ff - fl >= 64) {
                p.wcg[wp + lane] = (unsigned)wcL[b * 128 + ((fl + lane) & 127)];
                p.wrg[wp + lane] = wrL[b * 128 + ((fl + lane) & 127)];
                fl += 64; wp += 64;
            }
            if (lane == 0) { flsh[b] = fl; wpos[b] = wp; }
        }
        __syncthreads();
        Rcur = Rnext; Ccur = Cnext;
    }
    {   // drain
        const int wv = th >> 6, lane = th & 63;
        for (int k = 0; k < 16; ++k) {
            const int b = wv * 16 + k;
            int ff = fills[b], fl = flsh[b], wp = wpos[b];
            while (ff > fl) {
                int n = min(64, ff - fl);
                if (lane < n) {
                    p.wcg[wp + lane] = (unsigned)wcL[b * 128 + ((fl + lane) & 127)];
                    p.wrg[wp + lane] = wrL[b * 128 + ((fl + lane) & 127)];
                }
                fl += n; wp += n;
            }
        }
    }
}

// gather 8 w values for one batch; save the rl word alongside
#define GATH(G, CA, CB)                              \
    G##0 = w[(unsigned)CA.x]; G##1 = w[(unsigned)CA.y]; \
    G##2 = w[(unsigned)CA.z]; G##3 = w[(unsigned)CA.w]; \
    G##4 = w[(unsigned)CB.x]; G##5 = w[(unsigned)CB.y]; \
    G##6 = w[(unsigned)CB.z]; G##7 = w[(unsigned)CB.w];

#define ATOM(RL, G)                                                         \
    atomicAdd(&SH[RL.x & 0xFFFFu], __float2int_rn(G##0 * SCALE));           \
    atomicAdd(&SH[RL.x >> 16],     __float2int_rn(G##1 * SCALE));           \
    atomicAdd(&SH[RL.y & 0xFFFFu], __float2int_rn(G##2 * SCALE));           \
    atomicAdd(&SH[RL.y >> 16],     __float2int_rn(G##3 * SCALE));           \
    atomicAdd(&SH[RL.z & 0xFFFFu], __float2int_rn(G##4 * SCALE));           \
    atomicAdd(&SH[RL.z >> 16],     __float2int_rn(G##5 * SCALE));           \
    atomicAdd(&SH[RL.w & 0xFFFFu], __float2int_rn(G##6 * SCALE));           \
    atomicAdd(&SH[RL.w >> 16],     __float2int_rn(G##7 * SCALE));

// ---------------- K5: cooperative iteration loop (early exit) ----------------
__global__ __launch_bounds__(256, 2)
void k5_iter(const int* __restrict__ e32, const long long* __restrict__ e64,
             char* __restrict__ ws, float* __restrict__ out)
{
    cg::grid_group grid = cg::this_grid();
    P p = mk(ws);
    const int th = threadIdx.x, blk = blockIdx.x;
    const int tid = blk * T + th;
    const int stride = gridDim.x * T;
    __shared__ int SH[16384];
    __shared__ float sred[4];

    if (p.flags[0] || *p.ovf) {
        atomic_fallback(grid, (int)p.flags[0], e32, e64,
                        (int*)ws, (int*)(ws + (size_t)4*1024*1024), p.rdeg,
                        (float*)(ws + (size_t)8*1024*1024),
                        (float*)(ws + (size_t)12*1024*1024),
                        (float*)(ws + (size_t)16*1024*1024),
                        p.errF, out, tid, stride, th);
        return;
    }

    for (int iter = 0; iter < MAX_ITER; ++iter) {
        if (blk < NSUBB) {
            const int b = blk >> 3, sub = blk & 7;
            for (int j = th; j < 16384; j += T) SH[j] = 0;
            __syncthreads();
            const unsigned bs = p.baseR[b], tot = p.totR[b], pt = (tot + 7u) & ~7u;
            const unsigned nq = pt >> 3;
            const unsigned qlo = (nq * (unsigned)sub) >> 3;
            const unsigned qhi = (nq * (unsigned)(sub + 1)) >> 3;
            const vu4* __restrict__ r8 = (const vu4*)p.wrg + (bs >> 3);
            const vi4* __restrict__ c8 = (const vi4*)p.wcg + (bs >> 2);
            const float* __restrict__ w = p.w;

            // 3-stage pipeline: vec loads 2 batches ahead, gathers 1 ahead,
            // static even/odd renaming (no runtime-indexed arrays).
            unsigned q = qlo + th;
            vu4 rlA = {0,0,0,0}, rlB = {0,0,0,0}, rgA = {0,0,0,0}, rgB = {0,0,0,0};
            vi4 caA = {0,0,0,0}, cbA = {0,0,0,0}, caB = {0,0,0,0}, cbB = {0,0,0,0};
            float gA0=0,gA1=0,gA2=0,gA3=0,gA4=0,gA5=0,gA6=0,gA7=0;
            float gB0=0,gB1=0,gB2=0,gB3=0,gB4=0,gB5=0,gB6=0,gB7=0;
            if (q < qhi)     { rlA = r8[q];     caA = c8[2*q];       cbA = c8[2*q+1]; }
            if (q + T < qhi) { rlB = r8[q+T];   caB = c8[2*(q+T)];   cbB = c8[2*(q+T)+1]; }
            if (q < qhi)     { GATH(gA, caA, cbA); rgA = rlA; }
            while (q < qhi) {
                // even: gather B (issued before A's atomics), prefetch vec q+2T into A slots
                if (q + T < qhi)   { GATH(gB, caB, cbB); rgB = rlB; }
                if (q + 2*T < qhi) { rlA = r8[q+2*T]; caA = c8[2*(q+2*T)]; cbA = c8[2*(q+2*T)+1]; }
                ATOM(rgA, gA);
                q += T;
                if (q >= qhi) break;
                // odd: gather A, prefetch vec q+2T into B slots
                if (q + T < qhi)   { GATH(gA, caA, cbA); rgA = rlA; }
                if (q + 2*T < qhi) { rlB = r8[q+2*T]; caB = c8[2*(q+2*T)]; cbB = c8[2*(q+2*T)+1]; }
                ATOM(rgB, gB);
                q += T;
            }
            __syncthreads();
            vi4* pa = (vi4*)(p.pacc + (size_t)blk * 16384);
            const vi4* s4 = (const vi4*)SH;
            for (int j = th; j < 4096; j += T)
                __builtin_nontemporal_store(s4[j], pa + j);
        }
        grid.sync();

        float pe = 0.0f;
        if (blk < NSLC) {
            const int b = blk >> 3, off = (blk & 7) * 2048;
            for (int g = th; g < 512; g += T) {
                int node = b * BKN + off + 4 * g;
                if (node < NN) {
                    vi4 acc = {0, 0, 0, 0};
                    #pragma unroll
                    for (int qq = 0; qq < 8; ++qq) {
                        const vi4* pp = (const vi4*)(p.pacc + (size_t)(b*8+qq)*16384 + off);
                        vi4 x = ntload(pp + g);
                        acc.x += x.x; acc.y += x.y; acc.z += x.z; acc.w += x.w;
                    }
                    float x0 = TELEPORT + (float)acc.x * INVSCALE;
                    float x1 = TELEPORT + (float)acc.y * INVSCALE;
                    float x2 = TELEPORT + (float)acc.z * INVSCALE;
                    float x3 = TELEPORT + (float)acc.w * INVSCALE;
                    float4 prev;
                    if (iter == 0) prev = make_float4(INV_N, INV_N, INV_N, INV_N);
                    else           prev = *(const float4*)&out[node];
                    pe += fabsf(x0 - prev.x) + fabsf(x1 - prev.y)
                        + fabsf(x2 - prev.z) + fabsf(x3 - prev.w);
                    float4 nv = {x0, x1, x2, x3};
                    *(float4*)&out[node] = nv;                 // v lives in out
                    float4 rd = *(const float4*)&p.rdeg[node];
                    float4 nw = {x0*rd.x, x1*rd.y, x2*rd.z, x3*rd.w};
                    *(float4*)&p.w[node] = nw;                 // fused next phase A
                }
            }
            #pragma unroll
            for (int o2 = 32; o2 > 0; o2 >>= 1) pe += __shfl_down(pe, o2, 64);
            if ((th & 63) == 0) sred[th >> 6] = pe;
            __syncthreads();
            if (th == 0)
                unsafeAtomicAdd(&p.errF[iter], sred[0] + sred[1] + sred[2] + sred[3]);
        }
        grid.sync();
        const float e = ((volatile float*)p.errF)[iter];
        if (e < THRESH) break;
    }
}

// ---- emergency fallback kernel (ws too small / occupancy short) ----
__global__ __launch_bounds__(256, 4)
void pagerank_atomic(const int* __restrict__ e32, const long long* __restrict__ e64,
                     int* __restrict__ ai, int* __restrict__ deg,
                     float* __restrict__ rdeg, float* __restrict__ vA,
                     float* __restrict__ vB, float* __restrict__ w,
                     float* __restrict__ err, int* __restrict__ flags,
                     float* __restrict__ out)
{
    cg::grid_group grid = cg::this_grid();
    const int tid = blockIdx.x * blockDim.x + threadIdx.x;
    const int stride = gridDim.x * blockDim.x;
    if (tid < MAX_ITER) err[tid] = 0.0f;
    if (tid == 0) {
        int nz = 0;
        for (int k = 1; k < 512; k += 2) nz |= e32[k];
        flags[0] = (nz == 0) ? 1 : 0;
    }
    grid.sync();
    atomic_fallback(grid, flags[0], e32, e64, ai, deg, rdeg, vA, vB, w, err, out,
                    tid, stride, threadIdx.x);
}

extern "C" void kernel_launch(void* const* d_in, const int* in_sizes, int n_in,
                              void* d_out, int out_size, void* d_ws, size_t ws_size,
                              hipStream_t stream)
{
    (void)n_in; (void)out_size; (void)in_sizes;
    const int*       e32 = (const int*)d_in[1];
    const long long* e64 = (const long long*)d_in[1];
    float* out = (float*)d_out;
    char*  ws  = (char*)d_ws;

    int occ = 0;
    hipOccupancyMaxActiveBlocksPerMultiprocessor(&occ, (const void*)k5_iter, T, 0);

    if (ws_size >= NEED && occ >= 2) {
        k0_init<<<1,    T, 0, stream>>>(e32, ws);
        k1_hist<<<NCH,  T, 0, stream>>>(e32, ws);
        k2_scan<<<128,  T, 0, stream>>>(ws);
        k2b_bases<<<1,  T, 0, stream>>>(ws);
        k3a_col<<<NCH,  T, 0, stream>>>(e32, ws);
        k4_deg<<<NBKU,  T, 0, stream>>>(ws);
        k3b_row<<<NCH,  T, 0, stream>>>(e32, ws);
        void* args[] = { (void*)&e32, (void*)&e64, (void*)&ws, (void*)&out };
        hipLaunchCooperativeKernel((const void*)k5_iter,
                                   dim3(512), dim3(T), args, 0, stream);
        return;
    }

    // emergency: device-atomic version, small footprint
    const size_t MB = 1024 * 1024;
    int*   ai    = (int*)(ws);
    int*   deg   = (int*)(ws + 4 * MB);
    float* rdeg  = (float*)(ws + 8 * MB);
    float* vA    = (float*)(ws + 12 * MB);
    float* vB    = (float*)(ws + 16 * MB);
    float* w     = (float*)(ws + 20 * MB);
    float* err   = (float*)(ws + 24 * MB);
    int*   flg   = (int*)(ws + 24 * MB + 4096);
    int occ2 = 0;
    hipOccupancyMaxActiveBlocksPerMultiprocessor(&occ2, (const void*)pagerank_atomic, 256, 0);
    if (occ2 < 1) occ2 = 1;
    int grid = occ2 * 256; if (grid > 2048) grid = 2048;
    void* args[] = { (void*)&e32, (void*)&e64, (void*)&ai, (void*)&deg, (void*)&rdeg,
                     (void*)&vA, (void*)&vB, (void*)&w, (void*)&err, (void*)&flg,
                     (void*)&out };
    hipLaunchCooperativeKernel((const void*)pagerank_atomic,
                               dim3(grid), dim3(256), args, 0, stream);
}

// Round 4
// 518.830 us; speedup vs baseline: 2.1166x; 1.2443x over previous
//
#include <hip/hip_runtime.h>
#include <hip/hip_cooperative_groups.h>

namespace cg = cooperative_groups;

// PageRank R12. R11 post-mortem: 3-stage pipeline NULL (242 vs 250us) ->
// scatter is gather-THROUGHPUT bound (divergent w[col]: 62.5K unique lines/CU
// serialized in TA/L1), not latency-chain bound; pipelines can't beat a
// throughput limit. Monolithic coop k5 hides phase attribution (top-5 = k5
// replays only). R12: split iteration 0 into plain kernels k5a_scatter (512
// thr = 4 waves/SIMD feed, ntload streams restored to keep L2 clean for w)
// + k5b_merge; coop k5c handles iters>=1 and exits immediately on
// convergence (this input converges at iter 0). Gives per-phase rocprof
// timing + removes 2 grid syncs. Partition machinery unchanged from R11.

static constexpr int   NN       = 1000000;
static constexpr int   NE       = 16000000;
static constexpr float ALPHA    = 0.85f;
static constexpr int   MAX_ITER = 100;
static constexpr float THRESH   = 1.0f;                      // float32(N)*1e-6
static constexpr float INV_N    = 1.0f / 1000000.0f;
static constexpr float TELEPORT = 0.15f * (1.0f / 1000000.0f);
static constexpr float SCALE    = 8796093022208.0f;          // 2^43
static constexpr float INVSCALE = 1.0f / 8796093022208.0f;

static constexpr int T     = 256;
static constexpr int T5    = 512;            // k5a block size
static constexpr int NCH   = 2048;           // partition chunks (=K1/K3 grids)
static constexpr int BSH   = 14;
static constexpr int BKN   = 16384;          // nodes per bucket
static constexpr int NBK   = 64;             // buckets (62 used)
static constexpr int NBKU  = 62;             // used buckets
static constexpr int NSUBB = 496;            // 62 x 8 SpMV partials
static constexpr int NSLC  = 489;            // 2048-node merge slices

// ws layout (bytes); colp overlays wcg (dead before K3b writes wcg)
static constexpr size_t OFF_WCG  = 0;                  // (NE+512) u32
static constexpr size_t OFF_COLP = 0;                  // (NE+512) u16 overlay
static constexpr size_t OFF_WRG  = 64002048;           // (NE+512) u16
static constexpr size_t OFF_PACC = 96003072;           // 496*16384 i32
static constexpr size_t OFF_CNTR = 128508928;          // 64*2048 u32
static constexpr size_t OFF_CNTC = 129033216;          // 64*2048 u32
static constexpr size_t OFF_CTRL = 129557504;          // 4KB
static constexpr size_t OFF_RDEG = 129561600;          // 4,000,000
static constexpr size_t OFF_W    = 133561600;          // 4,000,032 (w[NN]=0)
static constexpr size_t NEED     = 137561632;

typedef int      vi4 __attribute__((ext_vector_type(4)));
typedef unsigned vu4 __attribute__((ext_vector_type(4)));

template<typename TT>
__device__ __forceinline__ TT ntload(const TT* p) { return __builtin_nontemporal_load(p); }

struct P {
    unsigned* wcg; unsigned short* colp; unsigned short* wrg;
    int* pacc; unsigned* cntR; unsigned* cntC;
    float* rdeg; float* w;
    unsigned* totR; unsigned* totC; unsigned* baseR; unsigned* baseC;
    unsigned* flags; int* ovf; float* errF;
};
__device__ __forceinline__ P mk(char* ws) {
    P p;
    p.wcg  = (unsigned*)(ws + OFF_WCG);
    p.colp = (unsigned short*)(ws + OFF_COLP);
    p.wrg  = (unsigned short*)(ws + OFF_WRG);
    p.pacc = (int*)(ws + OFF_PACC);
    p.cntR = (unsigned*)(ws + OFF_CNTR);
    p.cntC = (unsigned*)(ws + OFF_CNTC);
    unsigned* ctrl = (unsigned*)(ws + OFF_CTRL);
    p.rdeg = (float*)(ws + OFF_RDEG);
    p.w    = (float*)(ws + OFF_W);
    p.totR = ctrl; p.totC = ctrl + 64; p.baseR = ctrl + 128; p.baseC = ctrl + 200;
    p.flags = ctrl + 280; p.ovf = (int*)(ctrl + 281); p.errF = (float*)(ctrl + 288);
    return p;
}

// ---- atomic fallback (is64 input / ring overflow / small ws). No __shared__. ----
__device__ void atomic_fallback(cg::grid_group& grid, int is64,
                                const int* e32, const long long* e64,
                                int* ai, int* deg, float* rdeg,
                                float* vA, float* vB, float* w,
                                float* err, float* out,
                                int tid, int stride, int th)
{
    for (int i = tid; i < NN; i += stride) { ai[i] = 0; deg[i] = 0; vA[i] = INV_N; }
    grid.sync();
    if (is64) { const long long* cols = e64 + NE;
        for (int e = tid; e < NE; e += stride) atomicAdd(&deg[(int)cols[e]], 1); }
    else      { const int* cols = e32 + NE;
        for (int e = tid; e < NE; e += stride) atomicAdd(&deg[cols[e]], 1); }
    grid.sync();
    for (int i = tid; i < NN; i += stride) rdeg[i] = ALPHA / (float)deg[i];
    grid.sync();
    float* v = vA; float* nv = vB;
    for (int iter = 0; iter < MAX_ITER; ++iter) {
        for (int i = tid; i < NN; i += stride) { w[i] = v[i] * rdeg[i]; ai[i] = 0; }
        grid.sync();
        if (is64) { const long long* rows = e64; const long long* cols = e64 + NE;
            for (int e = tid; e < NE; e += stride)
                atomicAdd(&ai[(int)rows[e]], __float2int_rn(w[(int)cols[e]] * SCALE)); }
        else { const int* rows = e32; const int* cols = e32 + NE;
            for (int e = tid; e < NE; e += stride)
                atomicAdd(&ai[rows[e]], __float2int_rn(w[cols[e]] * SCALE)); }
        grid.sync();
        float pe = 0.0f;
        for (int i = tid; i < NN; i += stride) {
            float x = TELEPORT + (float)ai[i] * INVSCALE;
            pe += fabsf(x - v[i]); nv[i] = x;
        }
        #pragma unroll
        for (int off = 32; off > 0; off >>= 1) pe += __shfl_down(pe, off, 64);
        if ((th & 63) == 0) unsafeAtomicAdd(&err[iter], pe);
        grid.sync();
        float e = ((volatile float*)err)[iter];
        float* t = v; v = nv; nv = t;
        if (e < THRESH) break;
    }
    for (int i = tid; i < NN; i += stride) out[i] = v[i];
}

// ---------------- K0: flags / control init ----------------
__global__ __launch_bounds__(256) void k0_init(const int* __restrict__ e32, char* ws)
{
    P p = mk(ws);
    __shared__ int snz;
    const int th = threadIdx.x;
    if (th == 0) snz = 0;
    __syncthreads();
    if (e32[2 * th + 1] != 0) atomicOr(&snz, 1);   // int64 => high words all 0
    __syncthreads();
    if (th == 0) { p.flags[0] = (snz == 0) ? 1u : 0u; *p.ovf = 0; p.w[NN] = 0.0f; }
    if (th < MAX_ITER) p.errF[th] = 0.0f;
}

// ---------------- K1: per-chunk bucket histograms (rows + cols, LDS only) ----------------
__global__ __launch_bounds__(256, 8) void k1_hist(const int* __restrict__ e32, char* ws)
{
    P p = mk(ws);
    if (p.flags[0]) return;
    __shared__ int h[128];
    const int th = threadIdx.x, blk = blockIdx.x;
    const int e0 = (int)(((long long)NE * blk) >> 11);
    const int e1 = (int)(((long long)NE * (blk + 1)) >> 11);
    if (th < 128) h[th] = 0;
    __syncthreads();
    const vi4* R4 = (const vi4*)e32;
    const vi4* C4 = (const vi4*)(e32 + NE);
    const int qe = (e1 + 3) >> 2;
    for (int q = (e0 >> 2) + th; q < qe; q += T) {
        vi4 R = R4[q], C = C4[q];                  // plain loads: seed L3 for K3
        int rr[4] = {R.x, R.y, R.z, R.w}, cc[4] = {C.x, C.y, C.z, C.w};
        #pragma unroll
        for (int j = 0; j < 4; ++j) {
            int e = 4 * q + j;
            if (e >= e0 && e < e1) {
                atomicAdd(&h[rr[j] >> BSH], 1);
                atomicAdd(&h[64 + (cc[j] >> BSH)], 1);
            }
        }
    }
    __syncthreads();
    if (th < 64) {
        p.cntR[(size_t)th * NCH + blk] = (unsigned)h[th];
        p.cntC[(size_t)th * NCH + blk] = (unsigned)h[64 + th];
    }
}

// ---------------- K2: per-bucket exclusive scan over 2048 chunks ----------------
__global__ __launch_bounds__(256, 4) void k2_scan(char* ws)
{
    P p = mk(ws);
    if (p.flags[0]) return;
    __shared__ int S[256];
    const int th = threadIdx.x, blk = blockIdx.x;     // 128 blocks
    const int side = blk >> 6, b = blk & 63;
    unsigned* cnt = (side ? p.cntC : p.cntR) + (size_t)b * NCH;
    unsigned v[8]; unsigned s = 0;
    #pragma unroll
    for (int i = 0; i < 8; ++i) { v[i] = cnt[8 * th + i]; s += v[i]; }
    S[th] = (int)s; __syncthreads();
    for (int off = 1; off < 256; off <<= 1) {
        int x = (th >= off) ? S[th - off] : 0;
        __syncthreads(); S[th] += x; __syncthreads();
    }
    unsigned run = (unsigned)S[th] - s;
    #pragma unroll
    for (int i = 0; i < 8; ++i) { unsigned t = v[i]; cnt[8 * th + i] = run; run += t; }
    if (th == 255) (side ? p.totC : p.totR)[b] = run;
}

// ---------------- K2b: padded bases + col pads ----------------
__global__ __launch_bounds__(256) void k2b_bases(char* ws)
{
    P p = mk(ws);
    if (p.flags[0]) return;
    __shared__ int S[128];
    const int th = threadIdx.x;
    unsigned pt = 0;
    if (th < 128) {
        unsigned t = (th < 64) ? p.totR[th] : p.totC[th - 64];
        pt = (t + 7u) & ~7u;
        S[th] = (int)pt;
    }
    __syncthreads();
    for (int off = 1; off < 64; off <<= 1) {
        int x = (th < 128 && (th & 63) >= off) ? S[th - off] : 0;
        __syncthreads(); if (th < 128) S[th] += x; __syncthreads();
    }
    if (th < 64) {
        p.baseR[th] = (unsigned)S[th] - pt;
        if (th == 63) p.baseR[64] = (unsigned)S[63];
    } else if (th < 128) {
        p.baseC[th - 64] = (unsigned)S[th] - pt;
        if (th == 127) p.baseC[64] = (unsigned)S[127];
    }
    __syncthreads();
    if (th < 64) {                                   // col pads (deg corrected in K4)
        unsigned tot = p.totC[th], bs = p.baseC[th], pp = (tot + 7u) & ~7u;
        for (unsigned i = tot; i < pp; ++i) p.colp[bs + i] = 0;
    }
}

// ---------------- K3a: col scatter (u16), register-pipelined ----------------
__global__ __launch_bounds__(256, 6) void k3a_col(const int* __restrict__ e32, char* ws)
{
    P p = mk(ws);
    if (p.flags[0]) return;
    __shared__ int SH3[4288];
    unsigned short* pcL = (unsigned short*)SH3;              // [64][128]
    int* fills = SH3 + 4096; int* flsh = SH3 + 4160; int* wpos = SH3 + 4224;
    const int th = threadIdx.x, blk = blockIdx.x;
    if (th < 64) { fills[th] = 0; flsh[th] = 0;
                   wpos[th] = (int)(p.baseC[th] + p.cntC[(size_t)th * NCH + blk]); }
    __syncthreads();
    const int e0 = (int)(((long long)NE * blk) >> 11);
    const int e1 = (int)(((long long)NE * (blk + 1)) >> 11);
    const vi4* C4 = (const vi4*)(e32 + NE);
    const int qs = e0 >> 2, qe = (e1 + 3) >> 2;
    vi4 Ccur = {0, 0, 0, 0}; if (qs + th < qe) Ccur = C4[qs + th];
    for (int qb = qs; qb < qe; qb += T) {
        vi4 Cnext = {0, 0, 0, 0};
        { int qn = qb + T + th; if (qn < qe) Cnext = C4[qn]; }   // prefetch next batch
        const int q = qb + th;
        if (q < qe) {
            int cc[4] = {Ccur.x, Ccur.y, Ccur.z, Ccur.w};
            #pragma unroll
            for (int j = 0; j < 4; ++j) {
                int e = 4 * q + j;
                if (e >= e0 && e < e1) {
                    int bb = cc[j] >> BSH;
                    int idx = atomicAdd(&fills[bb], 1);
                    pcL[bb * 128 + (idx & 127)] = (unsigned short)(cc[j] & (BKN - 1));
                }
            }
        }
        __syncthreads();
        const int wv = th >> 6, lane = th & 63;
        for (int k = 0; k < 16; ++k) {
            const int b = wv * 16 + k;
            int ff = fills[b], fl = flsh[b], wp = wpos[b];
            if (ff - fl > 128) *p.ovf = 1;
            while (ff - fl >= 64) {
                p.colp[wp + lane] = pcL[b * 128 + ((fl + lane) & 127)];
                fl += 64; wp += 64;
            }
            if (lane == 0) { flsh[b] = fl; wpos[b] = wp; }
        }
        __syncthreads();
        Ccur = Cnext;
    }
    {   // drain
        const int wv = th >> 6, lane = th & 63;
        for (int k = 0; k < 16; ++k) {
            const int b = wv * 16 + k;
            int ff = fills[b], fl = flsh[b], wp = wpos[b];
            while (ff > fl) {
                int n = min(64, ff - fl);
                if (lane < n) p.colp[wp + lane] = pcL[b * 128 + ((fl + lane) & 127)];
                fl += n; wp += n;
            }
        }
    }
}

// ---------------- K4: fused per-bucket deg histogram -> rdeg, w0 ----------------
__global__ __launch_bounds__(256, 2) void k4_deg(char* ws)
{
    P p = mk(ws);
    if (p.flags[0] || *p.ovf) return;
    __shared__ int SH[16384];
    const int th = threadIdx.x, b = blockIdx.x;              // 62 blocks
    for (int j = th; j < 16384; j += T) SH[j] = 0;
    __syncthreads();
    const unsigned bs = p.baseC[b], tot = p.totC[b], pt = (tot + 7u) & ~7u;
    const unsigned nq = pt >> 3;
    const vu4* p8 = (const vu4*)p.colp + (bs >> 3);
    for (unsigned q = th; q < nq; q += T) {
        vu4 x = ntload(p8 + q);
        atomicAdd(&SH[x.x & 0xFFFFu], 1); atomicAdd(&SH[x.x >> 16], 1);
        atomicAdd(&SH[x.y & 0xFFFFu], 1); atomicAdd(&SH[x.y >> 16], 1);
        atomicAdd(&SH[x.z & 0xFFFFu], 1); atomicAdd(&SH[x.z >> 16], 1);
        atomicAdd(&SH[x.w & 0xFFFFu], 1); atomicAdd(&SH[x.w >> 16], 1);
    }
    __syncthreads();
    if (th == 0) SH[0] -= (int)(pt - tot);                   // pad correction
    __syncthreads();
    for (int g = th; g < 4096; g += T) {
        int node = b * BKN + 4 * g;
        if (node < NN) {                                     // node 4-aligned; NN%4==0
            float r0 = ALPHA / (float)SH[4*g+0];             // deg==0 -> inf, never gathered
            float r1 = ALPHA / (float)SH[4*g+1];
            float r2 = ALPHA / (float)SH[4*g+2];
            float r3 = ALPHA / (float)SH[4*g+3];
            float4 rr = {r0, r1, r2, r3};
            *(float4*)&p.rdeg[node] = rr;
            float4 ww = {INV_N * r0, INV_N * r1, INV_N * r2, INV_N * r3};
            *(float4*)&p.w[node] = ww;                       // fused iter-0 phase A
        }
    }
}

// ---------------- K3b: row scatter (u32 c + u16 r_low), register-pipelined ----------------
__global__ __launch_bounds__(256, 3) void k3b_row(const int* __restrict__ e32, char* ws)
{
    P p = mk(ws);
    if (p.flags[0] || *p.ovf) return;
    __shared__ int SH3[12480];
    int*            wcL = SH3;                               // [64][128] u32
    unsigned short* wrL = (unsigned short*)(SH3 + 8192);     // [64][128] u16
    int* fills = SH3 + 12288; int* flsh = SH3 + 12352; int* wpos = SH3 + 12416;
    const int th = threadIdx.x, blk = blockIdx.x;
    if (blk < 64 && th == 0) {                               // row pads
        unsigned tot = p.totR[blk], bs = p.baseR[blk], pt = (tot + 7u) & ~7u;
        for (unsigned i = tot; i < pt; ++i) { p.wcg[bs + i] = (unsigned)NN; p.wrg[bs + i] = 0; }
    }
    if (th < 64) { fills[th] = 0; flsh[th] = 0;
                   wpos[th] = (int)(p.baseR[th] + p.cntR[(size_t)th * NCH + blk]); }
    __syncthreads();
    const int e0 = (int)(((long long)NE * blk) >> 11);
    const int e1 = (int)(((long long)NE * (blk + 1)) >> 11);
    const vi4* R4 = (const vi4*)e32;
    const vi4* C4 = (const vi4*)(e32 + NE);
    const int qs = e0 >> 2, qe = (e1 + 3) >> 2;
    vi4 Rcur = {0,0,0,0}, Ccur = {0,0,0,0};
    if (qs + th < qe) { Rcur = R4[qs + th]; Ccur = C4[qs + th]; }
    for (int qb = qs; qb < qe; qb += T) {
        vi4 Rnext = {0,0,0,0}, Cnext = {0,0,0,0};
        { int qn = qb + T + th; if (qn < qe) { Rnext = R4[qn]; Cnext = C4[qn]; } }
        const int q = qb + th;
        if (q < qe) {
            int rr[4] = {Rcur.x, Rcur.y, Rcur.z, Rcur.w};
            int cc[4] = {Ccur.x, Ccur.y, Ccur.z, Ccur.w};
            #pragma unroll
            for (int j = 0; j < 4; ++j) {
                int e = 4 * q + j;
                if (e >= e0 && e < e1) {
                    int bb = rr[j] >> BSH;
                    int idx = atomicAdd(&fills[bb], 1);
                    int sl = idx & 127;
                    wcL[bb * 128 + sl] = cc[j];
                    wrL[bb * 128 + sl] = (unsigned short)(rr[j] & (BKN - 1));
                }
            }
        }
        __syncthreads();
        const int wv = th >> 6, lane = th & 63;
        for (int k = 0; k < 16; ++k) {
            const int b = wv * 16 + k;
            int ff = fills[b], fl = flsh[b], wp = wpos[b];
            if (ff - fl > 128) *p.ovf = 1;
            while (ff - fl >= 64) {
                p.wcg[wp + lane] = (unsigned)wcL[b * 128 + ((fl + lane) & 127)];
                p.wrg[wp + lane] = wrL[b * 128 + ((fl + lane) & 127)];
                fl += 64; wp += 64;
            }
            if (lane == 0) { flsh[b] = fl; wpos[b] = wp; }
        }
        __syncthreads();
        Rcur = Rnext; Ccur = Cnext;
    }
    {   // drain
        const int wv = th >> 6, lane = th & 63;
        for (int k = 0; k < 16; ++k) {
            const int b = wv * 16 + k;
            int ff = fills[b], fl = flsh[b], wp = wpos[b];
            while (ff > fl) {
                int n = min(64, ff - fl);
                if (lane < n) {
                    p.wcg[wp + lane] = (unsigned)wcL[b * 128 + ((fl + lane) & 127)];
                    p.wrg[wp + lane] = wrL[b * 128 + ((fl + lane) & 127)];
                }
                fl += n; wp += n;
            }
        }
    }
}

// gather 8 w values for one batch; save the rl word alongside
#define GATH(G, CA, CB)                              \
    G##0 = w[(unsigned)CA.x]; G##1 = w[(unsigned)CA.y]; \
    G##2 = w[(unsigned)CA.z]; G##3 = w[(unsigned)CA.w]; \
    G##4 = w[(unsigned)CB.x]; G##5 = w[(unsigned)CB.y]; \
    G##6 = w[(unsigned)CB.z]; G##7 = w[(unsigned)CB.w];

#define ATOM(RL, G)                                                         \
    atomicAdd(&SH[RL.x & 0xFFFFu], __float2int_rn(G##0 * SCALE));           \
    atomicAdd(&SH[RL.x >> 16],     __float2int_rn(G##1 * SCALE));           \
    atomicAdd(&SH[RL.y & 0xFFFFu], __float2int_rn(G##2 * SCALE));           \
    atomicAdd(&SH[RL.y >> 16],     __float2int_rn(G##3 * SCALE));           \
    atomicAdd(&SH[RL.z & 0xFFFFu], __float2int_rn(G##4 * SCALE));           \
    atomicAdd(&SH[RL.z >> 16],     __float2int_rn(G##5 * SCALE));           \
    atomicAdd(&SH[RL.w & 0xFFFFu], __float2int_rn(G##6 * SCALE));           \
    atomicAdd(&SH[RL.w >> 16],     __float2int_rn(G##7 * SCALE));

// ---------------- shared phase bodies (scatter / merge) ----------------
template<int TT>
__device__ __forceinline__ void scatter_phase(const P& p, int* SH, int th, int blk)
{
    const int b = blk >> 3, sub = blk & 7;
    for (int j = th; j < 16384; j += TT) SH[j] = 0;
    __syncthreads();
    const unsigned bs = p.baseR[b], tot = p.totR[b], pt = (tot + 7u) & ~7u;
    const unsigned nq = pt >> 3;
    const unsigned qlo = (nq * (unsigned)sub) >> 3;
    const unsigned qhi = (nq * (unsigned)(sub + 1)) >> 3;
    const vu4* __restrict__ r8 = (const vu4*)p.wrg + (bs >> 3);
    const vi4* __restrict__ c8 = (const vi4*)p.wcg + (bs >> 2);
    const float* __restrict__ w = p.w;

    // 3-stage pipeline (kept from R10/R11; nt-loads on streams keep L2 clean for w)
    unsigned q = qlo + th;
    vu4 rlA = {0,0,0,0}, rlB = {0,0,0,0}, rgA = {0,0,0,0}, rgB = {0,0,0,0};
    vi4 caA = {0,0,0,0}, cbA = {0,0,0,0}, caB = {0,0,0,0}, cbB = {0,0,0,0};
    float gA0=0,gA1=0,gA2=0,gA3=0,gA4=0,gA5=0,gA6=0,gA7=0;
    float gB0=0,gB1=0,gB2=0,gB3=0,gB4=0,gB5=0,gB6=0,gB7=0;
    if (q < qhi)      { rlA = ntload(r8+q);      caA = ntload(c8+2*q);        cbA = ntload(c8+2*q+1); }
    if (q + TT < qhi) { rlB = ntload(r8+q+TT);   caB = ntload(c8+2*(q+TT));   cbB = ntload(c8+2*(q+TT)+1); }
    if (q < qhi)      { GATH(gA, caA, cbA); rgA = rlA; }
    while (q < qhi) {
        if (q + TT < qhi)   { GATH(gB, caB, cbB); rgB = rlB; }
        if (q + 2*TT < qhi) { rlA = ntload(r8+q+2*TT); caA = ntload(c8+2*(q+2*TT)); cbA = ntload(c8+2*(q+2*TT)+1); }
        ATOM(rgA, gA);
        q += TT;
        if (q >= qhi) break;
        if (q + TT < qhi)   { GATH(gA, caA, cbA); rgA = rlA; }
        if (q + 2*TT < qhi) { rlB = ntload(r8+q+2*TT); caB = ntload(c8+2*(q+2*TT)); cbB = ntload(c8+2*(q+2*TT)+1); }
        ATOM(rgB, gB);
        q += TT;
    }
    __syncthreads();
    vi4* pa = (vi4*)(p.pacc + (size_t)blk * 16384);
    const vi4* s4 = (const vi4*)SH;
    for (int j = th; j < 4096; j += TT)
        __builtin_nontemporal_store(s4[j], pa + j);
}

__device__ __forceinline__ void merge_phase(const P& p, float* out, int iter,
                                            int th, int blk, float* sred)
{
    float pe = 0.0f;
    const int b = blk >> 3, off = (blk & 7) * 2048;
    for (int g = th; g < 512; g += T) {
        int node = b * BKN + off + 4 * g;
        if (node < NN) {
            vi4 acc = {0, 0, 0, 0};
            #pragma unroll
            for (int qq = 0; qq < 8; ++qq) {
                const vi4* pp = (const vi4*)(p.pacc + (size_t)(b*8+qq)*16384 + off);
                vi4 x = ntload(pp + g);
                acc.x += x.x; acc.y += x.y; acc.z += x.z; acc.w += x.w;
            }
            float x0 = TELEPORT + (float)acc.x * INVSCALE;
            float x1 = TELEPORT + (float)acc.y * INVSCALE;
            float x2 = TELEPORT + (float)acc.z * INVSCALE;
            float x3 = TELEPORT + (float)acc.w * INVSCALE;
            float4 prev;
            if (iter == 0) prev = make_float4(INV_N, INV_N, INV_N, INV_N);
            else           prev = *(const float4*)&out[node];
            pe += fabsf(x0 - prev.x) + fabsf(x1 - prev.y)
                + fabsf(x2 - prev.z) + fabsf(x3 - prev.w);
            float4 nv = {x0, x1, x2, x3};
            *(float4*)&out[node] = nv;                 // v lives in out
            float4 rd = *(const float4*)&p.rdeg[node];
            float4 nw = {x0*rd.x, x1*rd.y, x2*rd.z, x3*rd.w};
            *(float4*)&p.w[node] = nw;                 // fused next phase A
        }
    }
    #pragma unroll
    for (int o2 = 32; o2 > 0; o2 >>= 1) pe += __shfl_down(pe, o2, 64);
    if ((th & 63) == 0) sred[th >> 6] = pe;
    __syncthreads();
    if (th == 0)
        unsafeAtomicAdd(&p.errF[iter], sred[0] + sred[1] + sred[2] + sred[3]);
}

// ---------------- K5a: iteration-0 scatter (plain, 512 threads) ----------------
__global__ __launch_bounds__(512, 2) void k5a_scatter(char* __restrict__ ws)
{
    P p = mk(ws);
    if (p.flags[0] || *p.ovf) return;
    __shared__ int SH[16384];
    scatter_phase<T5>(p, SH, threadIdx.x, blockIdx.x);
}

// ---------------- K5b: iteration-0 merge (plain) ----------------
__global__ __launch_bounds__(256, 4) void k5b_merge(char* __restrict__ ws,
                                                    float* __restrict__ out)
{
    P p = mk(ws);
    if (p.flags[0] || *p.ovf) return;
    __shared__ float sred[4];
    merge_phase(p, out, 0, threadIdx.x, blockIdx.x, sred);
}

// ---------------- K5c: cooperative loop for iterations >= 1 ----------------
__global__ __launch_bounds__(256, 2)
void k5c_iter(const int* __restrict__ e32, const long long* __restrict__ e64,
              char* __restrict__ ws, float* __restrict__ out)
{
    cg::grid_group grid = cg::this_grid();
    P p = mk(ws);
    const int th = threadIdx.x, blk = blockIdx.x;
    const int tid = blk * T + th;
    const int stride = gridDim.x * T;
    __shared__ int SH[16384];
    __shared__ float sred[4];

    if (p.flags[0] || *p.ovf) {
        atomic_fallback(grid, (int)p.flags[0], e32, e64,
                        (int*)ws, (int*)(ws + (size_t)4*1024*1024), p.rdeg,
                        (float*)(ws + (size_t)8*1024*1024),
                        (float*)(ws + (size_t)12*1024*1024),
                        (float*)(ws + (size_t)16*1024*1024),
                        p.errF, out, tid, stride, th);
        return;
    }

    for (int iter = 1; iter < MAX_ITER; ++iter) {
        const float e = ((volatile float*)p.errF)[iter - 1];
        if (e < THRESH) break;                       // converged at prev iter
        if (blk < NSUBB) scatter_phase<T>(p, SH, th, blk);
        grid.sync();
        if (blk < NSLC) merge_phase(p, out, iter, th, blk, sred);
        grid.sync();
    }
}

// ---- emergency fallback kernel (ws too small / occupancy short) ----
__global__ __launch_bounds__(256, 4)
void pagerank_atomic(const int* __restrict__ e32, const long long* __restrict__ e64,
                     int* __restrict__ ai, int* __restrict__ deg,
                     float* __restrict__ rdeg, float* __restrict__ vA,
                     float* __restrict__ vB, float* __restrict__ w,
                     float* __restrict__ err, int* __restrict__ flags,
                     float* __restrict__ out)
{
    cg::grid_group grid = cg::this_grid();
    const int tid = blockIdx.x * blockDim.x + threadIdx.x;
    const int stride = gridDim.x * blockDim.x;
    if (tid < MAX_ITER) err[tid] = 0.0f;
    if (tid == 0) {
        int nz = 0;
        for (int k = 1; k < 512; k += 2) nz |= e32[k];
        flags[0] = (nz == 0) ? 1 : 0;
    }
    grid.sync();
    atomic_fallback(grid, flags[0], e32, e64, ai, deg, rdeg, vA, vB, w, err, out,
                    tid, stride, threadIdx.x);
}

extern "C" void kernel_launch(void* const* d_in, const int* in_sizes, int n_in,
                              void* d_out, int out_size, void* d_ws, size_t ws_size,
                              hipStream_t stream)
{
    (void)n_in; (void)out_size; (void)in_sizes;
    const int*       e32 = (const int*)d_in[1];
    const long long* e64 = (const long long*)d_in[1];
    float* out = (float*)d_out;
    char*  ws  = (char*)d_ws;

    int occ = 0;
    hipOccupancyMaxActiveBlocksPerMultiprocessor(&occ, (const void*)k5c_iter, T, 0);

    if (ws_size >= NEED && occ >= 2) {
        k0_init<<<1,    T, 0, stream>>>(e32, ws);
        k1_hist<<<NCH,  T, 0, stream>>>(e32, ws);
        k2_scan<<<128,  T, 0, stream>>>(ws);
        k2b_bases<<<1,  T, 0, stream>>>(ws);
        k3a_col<<<NCH,  T, 0, stream>>>(e32, ws);
        k4_deg<<<NBKU,  T, 0, stream>>>(ws);
        k3b_row<<<NCH,  T, 0, stream>>>(e32, ws);
        k5a_scatter<<<NSUBB, T5, 0, stream>>>(ws);
        k5b_merge<<<NSLC, T, 0, stream>>>(ws, out);
        void* args[] = { (void*)&e32, (void*)&e64, (void*)&ws, (void*)&out };
        hipLaunchCooperativeKernel((const void*)k5c_iter,
                                   dim3(512), dim3(T), args, 0, stream);
        return;
    }

    // emergency: device-atomic version, small footprint
    const size_t MB = 1024 * 1024;
    int*   ai    = (int*)(ws);
    int*   deg   = (int*)(ws + 4 * MB);
    float* rdeg  = (float*)(ws + 8 * MB);
    float* vA    = (float*)(ws + 12 * MB);
    float* vB    = (float*)(ws + 16 * MB);
    float* w     = (float*)(ws + 20 * MB);
    float* err   = (float*)(ws + 24 * MB);
    int*   flg   = (int*)(ws + 24 * MB + 4096);
    int occ2 = 0;
    hipOccupancyMaxActiveBlocksPerMultiprocessor(&occ2, (const void*)pagerank_atomic, 256, 0);
    if (occ2 < 1) occ2 = 1;
    int grid = occ2 * 256; if (grid > 2048) grid = 2048;
    void* args[] = { (void*)&e32, (void*)&e64, (void*)&ai, (void*)&deg, (void*)&rdeg,
                     (void*)&vA, (void*)&vB, (void*)&w, (void*)&err, (void*)&flg,
                     (void*)&out };
    hipLaunchCooperativeKernel((const void*)pagerank_atomic,
                               dim3(grid), dim3(256), args, 0, stream);
}